// Round 1
// baseline (428420.801 us; speedup 1.0000x reference)
//
#include <hip/hip_runtime.h>

// ---------------- problem constants ----------------
#define PL 400
#define QL 60
#define BB 128
#define EE 512
#define HH 256
#define DD 1024
#define G3 768
#define NBLK 256
#define NTHR 256
#define LDK 72   // padded K stride (shorts) for LDS tiles

typedef __attribute__((ext_vector_type(8))) short bfrag;
typedef __attribute__((ext_vector_type(4))) float facc;

// ---------------- bf16 helpers ----------------
__device__ __forceinline__ unsigned short f2bf(float x) {
  unsigned u = __float_as_uint(x);
  return (unsigned short)((u + 0x7fffu + ((u >> 16) & 1u)) >> 16);
}
__device__ __forceinline__ float bf2f(unsigned short h) {
  return __uint_as_float(((unsigned)h) << 16);
}
__device__ __forceinline__ void split_bf(float x, unsigned short& hi, unsigned short& lo) {
  hi = f2bf(x);
  lo = f2bf(x - bf2f(hi));
}
__device__ __forceinline__ float sigm(float x) { return 1.f / (1.f + __expf(-x)); }

// ---------------- ws layout (element offsets) ----------------
// fp32 region
constexpr size_t SZ_QT  = (size_t)2 * QL * BB * HH;   // q_temp
constexpr size_t SZ_PT  = (size_t)2 * PL * BB * HH;   // p_temp
constexpr size_t SZ_H   = (size_t)2 * BB * HH;        // state
constexpr size_t SZ_GP  = (size_t)4 * 2 * BB * DD;    // gate partials (k-split 4)
constexpr size_t SZ_GIP = (size_t)4 * 2 * BB * G3;    // gi partials
constexpr size_t SZ_GHP = (size_t)2 * BB * G3;        // gh
constexpr size_t OFF_QT  = 0;
constexpr size_t OFF_PT  = OFF_QT + SZ_QT;
constexpr size_t OFF_H   = OFF_PT + SZ_PT;
constexpr size_t OFF_GP  = OFF_H + SZ_H;
constexpr size_t OFF_GIP = OFF_GP + SZ_GP;
constexpr size_t OFF_GHP = OFF_GIP + SZ_GIP;
constexpr size_t F32_TOT = OFF_GHP + SZ_GHP;
// bf16 (ushort) region
constexpr size_t HSZ_ATT = (size_t)2 * BB * EE;
constexpr size_t HSZ_WQT = (size_t)2 * HH * EE;
constexpr size_t HSZ_GW  = (size_t)2 * DD * DD;
constexpr size_t HSZ_WIH = (size_t)2 * G3 * DD;
constexpr size_t HSZ_WHH = (size_t)2 * G3 * HH;
constexpr size_t HOFF_ATTH = 0;
constexpr size_t HOFF_ATTL = HOFF_ATTH + HSZ_ATT;
constexpr size_t HOFF_WQTH = HOFF_ATTL + HSZ_ATT;
constexpr size_t HOFF_WQTL = HOFF_WQTH + HSZ_WQT;
constexpr size_t HOFF_WPTH = HOFF_WQTL + HSZ_WQT;
constexpr size_t HOFF_WPTL = HOFF_WPTH + HSZ_WQT;
constexpr size_t HOFF_GWH  = HOFF_WPTL + HSZ_WQT;
constexpr size_t HOFF_GWL  = HOFF_GWH + HSZ_GW;
constexpr size_t HOFF_WIHH = HOFF_GWL + HSZ_GW;
constexpr size_t HOFF_WIHL = HOFF_WIHH + HSZ_WIH;
constexpr size_t HOFF_WHHH = HOFF_WIHL + HSZ_WIH;
constexpr size_t HOFF_WHHL = HOFF_WHHH + HSZ_WHH;
constexpr size_t H_TOT     = HOFF_WHHL + HSZ_WHH;

// ---------------- grid barrier (custom, non-cooperative) ----------------
__device__ __forceinline__ void gbar(unsigned* bar, unsigned target) {
  __threadfence();
  __syncthreads();
  if (threadIdx.x == 0) {
    unsigned prev = __hip_atomic_fetch_add(&bar[0], 1u, __ATOMIC_ACQ_REL, __HIP_MEMORY_SCOPE_AGENT);
    if (prev == NBLK - 1) {
      __hip_atomic_store(&bar[0], 0u, __ATOMIC_RELAXED, __HIP_MEMORY_SCOPE_AGENT);
      __hip_atomic_fetch_add(&bar[1], 1u, __ATOMIC_RELEASE, __HIP_MEMORY_SCOPE_AGENT);
    } else {
      unsigned spins = 0;
      while (__hip_atomic_load(&bar[1], __ATOMIC_ACQUIRE, __HIP_MEMORY_SCOPE_AGENT) < target) {
        __builtin_amdgcn_s_sleep(2);
        if (++spins > (1u << 24)) break;  // hang bailout
      }
    }
  }
  __syncthreads();
  __threadfence();
}

// ---------------- 128x128 MFMA GEMM tile (hi/lo bf16 = fp32-accurate) ----------------
// AMODE 0: A = fp32 row-major src (asrc, astride), convert to hi/lo
// AMODE 1: A = u = [p_input(t) | att]  (p converted, att already bf16 hi/lo)
// AMODE 2: A = x = u * sigmoid(sum(gate partials) + gate_b)
template <int AMODE>
__device__ void gemm128(unsigned short* sAh, unsigned short* sAl,
                        unsigned short* sBh, unsigned short* sBl,
                        const float* asrc, size_t astride,
                        const float* pin_t, const unsigned short* atth_d, const unsigned short* attl_d,
                        const float* gp, const float* gateb_d, int d,
                        const unsigned short* bh, const unsigned short* bl, size_t bstride,
                        float* dst, size_t dstride,
                        int kbase, int nchunks) {
  const int tid = threadIdx.x;
  const int lane = tid & 63;
  const int w = tid >> 6;
  const int wm = (w >> 1) << 6;
  const int wn = (w & 1) << 6;
  const int lr = lane & 15;
  const int lk = (lane >> 4) << 3;

  const facc fz = {0.f, 0.f, 0.f, 0.f};
  facc acc[4][4];
#pragma unroll
  for (int i = 0; i < 4; i++) {
#pragma unroll
    for (int j = 0; j < 4; j++) acc[i][j] = fz;
  }

  for (int kc = 0; kc < nchunks; ++kc) {
    const int kk0 = kbase + (kc << 6);
    for (int i = tid; i < 8192; i += NTHR) {
      const int r = i >> 6, k = i & 63;
      const int kk = kk0 + k;
      unsigned short uh, ul;
      if constexpr (AMODE == 0) {
        split_bf(asrc[(size_t)r * astride + kk], uh, ul);
      } else if constexpr (AMODE == 1) {
        if (kk < EE) {
          split_bf(pin_t[(size_t)r * EE + kk], uh, ul);
        } else {
          size_t o = (size_t)r * EE + (kk - EE);
          uh = atth_d[o]; ul = attl_d[o];
        }
      } else {
        float g = gp[((size_t)(0 + d) * BB + r) * DD + kk]
                + gp[((size_t)(2 + d) * BB + r) * DD + kk]
                + gp[((size_t)(4 + d) * BB + r) * DD + kk]
                + gp[((size_t)(6 + d) * BB + r) * DD + kk]
                + gateb_d[kk];
        float u;
        if (kk < EE) {
          u = pin_t[(size_t)r * EE + kk];
        } else {
          size_t o = (size_t)r * EE + (kk - EE);
          u = bf2f(atth_d[o]) + bf2f(attl_d[o]);
        }
        split_bf(u * sigm(g), uh, ul);
      }
      sAh[r * LDK + k] = uh;
      sAl[r * LDK + k] = ul;
      size_t bo = (size_t)r * bstride + kk;  // r doubles as weight-row index
      sBh[r * LDK + k] = bh[bo];
      sBl[r * LDK + k] = bl[bo];
    }
    __syncthreads();
#pragma unroll
    for (int k32 = 0; k32 < 64; k32 += 32) {
      bfrag ah[4], al_[4], bhf[4], blf[4];
#pragma unroll
      for (int f = 0; f < 4; f++) {
        const int ao = (wm + (f << 4) + lr) * LDK + k32 + lk;
        ah[f]  = *(const bfrag*)&sAh[ao];
        al_[f] = *(const bfrag*)&sAl[ao];
        const int bo2 = (wn + (f << 4) + lr) * LDK + k32 + lk;
        bhf[f] = *(const bfrag*)&sBh[bo2];
        blf[f] = *(const bfrag*)&sBl[bo2];
      }
#pragma unroll
      for (int i = 0; i < 4; i++) {
#pragma unroll
        for (int j = 0; j < 4; j++) {
          acc[i][j] = __builtin_amdgcn_mfma_f32_16x16x32_bf16(al_[i], bhf[j], acc[i][j], 0, 0, 0);
          acc[i][j] = __builtin_amdgcn_mfma_f32_16x16x32_bf16(ah[i],  blf[j], acc[i][j], 0, 0, 0);
          acc[i][j] = __builtin_amdgcn_mfma_f32_16x16x32_bf16(ah[i],  bhf[j], acc[i][j], 0, 0, 0);
        }
      }
    }
    __syncthreads();
  }
  const int orow = (lane >> 4) << 2;
  const int ocol = lane & 15;
#pragma unroll
  for (int i = 0; i < 4; i++) {
#pragma unroll
    for (int j = 0; j < 4; j++) {
#pragma unroll
      for (int q = 0; q < 4; q++) {
        dst[(size_t)(wm + (i << 4) + orow + q) * dstride + (wn + (j << 4) + ocol)] = acc[i][j][q];
      }
    }
  }
}

// ---------------- setup kernels ----------------
__global__ void __launch_bounds__(256) k_transpose_qp(
    const float* __restrict__ Wq, const float* __restrict__ Wp,
    unsigned short* __restrict__ wqth, unsigned short* __restrict__ wqtl,
    unsigned short* __restrict__ wpth, unsigned short* __restrict__ wptl) {
  __shared__ float tile[64 * 65];
  const int blk = blockIdx.x;  // 128 blocks: mat(2) x d(2) x kt(8) x nt(4)
  const int mat = blk >> 6;
  const int rem = blk & 63;
  const int d = rem >> 5;
  const int rem2 = rem & 31;
  const int kt = rem2 >> 2;
  const int nt = rem2 & 3;
  const float* src = mat ? Wp : Wq;
  unsigned short* dh = mat ? wpth : wqth;
  unsigned short* dl = mat ? wptl : wqtl;
  const int tid = threadIdx.x;
  for (int i = tid; i < 4096; i += 256) {
    int kr = i >> 6, nc = i & 63;
    tile[kr * 65 + nc] = src[((size_t)d * EE + kt * 64 + kr) * HH + nt * 64 + nc];
  }
  __syncthreads();
  for (int i = tid; i < 4096; i += 256) {
    int n = i >> 6, k = i & 63;
    unsigned short hi, lo;
    split_bf(tile[k * 65 + n], hi, lo);
    size_t o = ((size_t)d * HH + nt * 64 + n) * EE + kt * 64 + k;
    dh[o] = hi; dl[o] = lo;
  }
}

__global__ void __launch_bounds__(256) k_split_w(
    const float* __restrict__ gw, const float* __restrict__ wih, const float* __restrict__ whh,
    unsigned short* __restrict__ gwh, unsigned short* __restrict__ gwl,
    unsigned short* __restrict__ wihh, unsigned short* __restrict__ wihl,
    unsigned short* __restrict__ whhh, unsigned short* __restrict__ whhl) {
  const size_t N1 = HSZ_GW, N2 = HSZ_WIH, N3 = HSZ_WHH;
  for (size_t i = (size_t)blockIdx.x * 256 + threadIdx.x; i < N1 + N2 + N3;
       i += (size_t)gridDim.x * 256) {
    float x; unsigned short *ph, *pl; size_t o;
    if (i < N1)           { o = i;           x = gw[o];  ph = gwh;  pl = gwl; }
    else if (i < N1 + N2) { o = i - N1;      x = wih[o]; ph = wihh; pl = wihl; }
    else                  { o = i - N1 - N2; x = whh[o]; ph = whhh; pl = whhl; }
    unsigned short hi, lo;
    split_bf(x, hi, lo);
    ph[o] = hi; pl[o] = lo;
  }
}

// ---------------- the persistent kernel ----------------
__global__ void __launch_bounds__(NTHR, 1) pe_main(
    const float* __restrict__ qin, const float* __restrict__ pin,
    const unsigned char* __restrict__ qmask,
    const float* __restrict__ Ws, const float* __restrict__ vvec,
    const float* __restrict__ gateb,
    const float* __restrict__ bih, const float* __restrict__ bhh,
    float* __restrict__ out,
    float* __restrict__ fws, unsigned short* __restrict__ hws,
    unsigned* __restrict__ bar) {
  __shared__ __align__(16) unsigned char smem_raw[73728];
  unsigned short* sAh = (unsigned short*)smem_raw;
  unsigned short* sAl = sAh + 128 * LDK;
  unsigned short* sBh = sAl + 128 * LDK;
  unsigned short* sBl = sBh + 128 * LDK;
  float* fsm = (float*)smem_raw;

  float* qt   = fws + OFF_QT;
  float* pt   = fws + OFF_PT;
  float* hbuf = fws + OFF_H;
  float* gp   = fws + OFF_GP;
  float* gip  = fws + OFF_GIP;
  float* ghp  = fws + OFF_GHP;
  unsigned short* atth = hws + HOFF_ATTH;
  unsigned short* attl = hws + HOFF_ATTL;
  unsigned short* wqth = hws + HOFF_WQTH;
  unsigned short* wqtl = hws + HOFF_WQTL;
  unsigned short* wpth = hws + HOFF_WPTH;
  unsigned short* wptl = hws + HOFF_WPTL;
  unsigned short* gwh  = hws + HOFF_GWH;
  unsigned short* gwl  = hws + HOFF_GWL;
  unsigned short* wihh = hws + HOFF_WIHH;
  unsigned short* wihl = hws + HOFF_WIHL;
  unsigned short* whhh = hws + HOFF_WHHH;
  unsigned short* whhl = hws + HOFF_WHHL;

  const int blk = blockIdx.x;
  const int tid = threadIdx.x;
  unsigned bt = 0;

  // ---- prologue: q_temp / p_temp GEMMs (1840 tile tasks) ----
  for (int tt = blk; tt < 1840; tt += NBLK) {
    if (tt < 1600) {
      int d = tt / 800, rem = tt % 800, mt = rem >> 1, nt = rem & 1;
      gemm128<0>(sAh, sAl, sBh, sBl,
                 pin + (size_t)mt * BB * EE, (size_t)EE,
                 nullptr, nullptr, nullptr, nullptr, nullptr, 0,
                 wpth + ((size_t)d * HH + (size_t)nt * 128) * EE,
                 wptl + ((size_t)d * HH + (size_t)nt * 128) * EE, (size_t)EE,
                 pt + ((size_t)d * PL * BB + (size_t)mt * BB) * HH + nt * 128, (size_t)HH,
                 0, 8);
    } else {
      int u2 = tt - 1600;
      int d = u2 / 120, rem = u2 % 120, mt = rem >> 1, nt = rem & 1;
      gemm128<0>(sAh, sAl, sBh, sBl,
                 qin + (size_t)mt * BB * EE, (size_t)EE,
                 nullptr, nullptr, nullptr, nullptr, nullptr, 0,
                 wqth + ((size_t)d * HH + (size_t)nt * 128) * EE,
                 wqtl + ((size_t)d * HH + (size_t)nt * 128) * EE, (size_t)EE,
                 qt + ((size_t)d * QL * BB + (size_t)mt * BB) * HH + nt * 128, (size_t)HH,
                 0, 8);
    }
  }
  gbar(bar, ++bt);

  const int d_ab = blk >> 7, b_ab = blk & 127;
  float stv = 0.f;  // this thread's state_temp[j=tid] for its (d,b); h starts at 0

  for (int s = 0; s < PL; ++s) {
    // ---------- phase A: attention ----------
    {
      const int d = d_ab, b = b_ab;
      const int t = d ? (PL - 1 - s) : s;
      float* sm = fsm;            // 256: p_t + state_temp
      float* sv = fsm + 256;      // 256: v
      float* slog = fsm + 512;    // 64: logits
      float* swgt = fsm + 576;    // 64: softmax weights
      sm[tid] = stv + pt[(((size_t)d * PL + t) * BB + b) * HH + tid];
      sv[tid] = vvec[d * HH + tid];
      __syncthreads();
      const int w = tid >> 6, lane = tid & 63;
      for (int q = w; q < QL; q += 4) {
        float a = 0.f;
#pragma unroll
        for (int jj = 0; jj < 4; jj++) {
          int j = lane + jj * 64;
          float qv = qt[(((size_t)d * QL + q) * BB + b) * HH + j];
          a += tanhf(qv + sm[j]) * sv[j];
        }
        for (int off = 32; off; off >>= 1) a += __shfl_down(a, off, 64);
        if (lane == 0) slog[q] = a;
      }
      __syncthreads();
      if (w == 0) {
        float x = -3.0e38f;
        if (lane < QL) {
          x = slog[lane];
          if (qmask[lane * BB + b]) x = -3.0e38f;
        }
        float mx = x;
        for (int off = 32; off; off >>= 1) mx = fmaxf(mx, __shfl_xor(mx, off, 64));
        float e = (lane < QL) ? __expf(x - mx) : 0.f;
        float sum2 = e;
        for (int off = 32; off; off >>= 1) sum2 += __shfl_xor(sum2, off, 64);
        if (lane < QL) swgt[lane] = e / sum2;
      }
      __syncthreads();
#pragma unroll
      for (int cc = 0; cc < 2; cc++) {
        int c = tid + cc * 256;
        float a = 0.f;
        for (int q = 0; q < QL; q++) a += swgt[q] * qin[((size_t)q * BB + b) * EE + c];
        unsigned short hi, lo;
        split_bf(a, hi, lo);
        atth[((size_t)d * BB + b) * EE + c] = hi;
        attl[((size_t)d * BB + b) * EE + c] = lo;
      }
    }
    gbar(bar, ++bt);

    // ---------- phase B: gate GEMM partials (k-split 4) ----------
    if (blk < 64) {
      const int d = blk >> 5, r5 = blk & 31, nt = r5 >> 2, ks = r5 & 3;
      const int t = d ? (PL - 1 - s) : s;
      gemm128<1>(sAh, sAl, sBh, sBl,
                 nullptr, 0,
                 pin + (size_t)t * BB * EE, atth + (size_t)d * BB * EE, attl + (size_t)d * BB * EE,
                 nullptr, nullptr, d,
                 gwh + ((size_t)d * DD + (size_t)nt * 128) * DD,
                 gwl + ((size_t)d * DD + (size_t)nt * 128) * DD, (size_t)DD,
                 gp + ((size_t)(ks * 2 + d) * BB) * DD + nt * 128, (size_t)DD,
                 ks * 256, 4);
    }
    gbar(bar, ++bt);

    // ---------- phase C1: gi partials (x gated inline) + gh ----------
    if (blk < 48) {
      const int d = blk / 24, rem = blk % 24, nt = rem >> 2, ks = rem & 3;
      const int t = d ? (PL - 1 - s) : s;
      gemm128<2>(sAh, sAl, sBh, sBl,
                 nullptr, 0,
                 pin + (size_t)t * BB * EE, atth + (size_t)d * BB * EE, attl + (size_t)d * BB * EE,
                 gp, gateb + (size_t)d * DD, d,
                 wihh + ((size_t)d * G3 + (size_t)nt * 128) * DD,
                 wihl + ((size_t)d * G3 + (size_t)nt * 128) * DD, (size_t)DD,
                 gip + ((size_t)(ks * 2 + d) * BB) * G3 + nt * 128, (size_t)G3,
                 ks * 256, 4);
    } else if (blk < 60) {
      const int m = blk - 48, d = m / 6, nt = m % 6;
      gemm128<0>(sAh, sAl, sBh, sBl,
                 hbuf + (size_t)d * BB * HH, (size_t)HH,
                 nullptr, nullptr, nullptr, nullptr, nullptr, 0,
                 whhh + ((size_t)d * G3 + (size_t)nt * 128) * HH,
                 whhl + ((size_t)d * G3 + (size_t)nt * 128) * HH, (size_t)HH,
                 ghp + ((size_t)d * BB) * G3 + nt * 128, (size_t)G3,
                 0, 4);
    }
    gbar(bar, ++bt);

    // ---------- phase C2: GRU elementwise + output + next state_temp ----------
    {
      const int d = d_ab, b = b_ab, j = tid;
      const int t = d ? (PL - 1 - s) : s;
      const size_t rb = (size_t)d * BB + b;
      float hp = hbuf[rb * HH + j];
      float gi0 = 0.f, gi1 = 0.f, gi2 = 0.f;
#pragma unroll
      for (int k2 = 0; k2 < 4; k2++) {
        size_t ro = ((size_t)(k2 * 2 + d) * BB + b) * G3;
        gi0 += gip[ro + j];
        gi1 += gip[ro + HH + j];
        gi2 += gip[ro + 2 * HH + j];
      }
      gi0 += bih[(size_t)d * G3 + j];
      gi1 += bih[(size_t)d * G3 + HH + j];
      gi2 += bih[(size_t)d * G3 + 2 * HH + j];
      size_t go = rb * G3;
      float gh0 = ghp[go + j] + bhh[(size_t)d * G3 + j];
      float gh1 = ghp[go + HH + j] + bhh[(size_t)d * G3 + HH + j];
      float gh2 = ghp[go + 2 * HH + j] + bhh[(size_t)d * G3 + 2 * HH + j];
      float r = sigm(gi0 + gh0);
      float z = sigm(gi1 + gh1);
      float n = tanhf(gi2 + r * gh2);
      float hn = (1.f - z) * n + z * hp;
      hbuf[rb * HH + j] = hn;
      out[((size_t)t * BB + b) * 512 + d * HH + j] = hn;
      float* hrow = fsm;
      hrow[j] = hn;
      __syncthreads();
      const float* Wsd = Ws + (size_t)d * HH * HH;
      float a2 = 0.f;
      for (int k = 0; k < HH; k += 4) {
        float4 h4 = *(const float4*)&hrow[k];
        a2 += h4.x * Wsd[(size_t)(k + 0) * HH + j] + h4.y * Wsd[(size_t)(k + 1) * HH + j]
            + h4.z * Wsd[(size_t)(k + 2) * HH + j] + h4.w * Wsd[(size_t)(k + 3) * HH + j];
      }
      stv = a2;  // state_temp for next step, stays in this thread's register
      __syncthreads();
    }
    // no barrier needed C2 -> A (A only uses intra-block data + static tensors)
  }
}

// ---------------- launch ----------------
extern "C" void kernel_launch(void* const* d_in, const int* in_sizes, int n_in,
                              void* d_out, int out_size, void* d_ws, size_t ws_size,
                              hipStream_t stream) {
  const float* qin = (const float*)d_in[0];
  const float* pin = (const float*)d_in[1];
  const unsigned char* qmask = (const unsigned char*)d_in[2];
  const float* Wq  = (const float*)d_in[3];
  const float* Wp  = (const float*)d_in[4];
  const float* Ws  = (const float*)d_in[5];
  const float* v   = (const float*)d_in[6];
  const float* gw  = (const float*)d_in[7];
  const float* gb  = (const float*)d_in[8];
  const float* wih = (const float*)d_in[9];
  const float* whh = (const float*)d_in[10];
  const float* bih = (const float*)d_in[11];
  const float* bhh = (const float*)d_in[12];
  float* out = (float*)d_out;

  float* fws = (float*)d_ws;
  unsigned short* hws = (unsigned short*)((char*)d_ws + F32_TOT * sizeof(float));
  unsigned* bar = (unsigned*)((char*)d_ws + F32_TOT * sizeof(float) + H_TOT * sizeof(unsigned short));
  size_t need = F32_TOT * sizeof(float) + H_TOT * sizeof(unsigned short) + 256;
  if (ws_size < need) return;  // ws too small — bail (output stays invalid)

  // zero the GRU state and the barrier
  hipMemsetAsync((char*)d_ws + OFF_H * sizeof(float), 0, SZ_H * sizeof(float), stream);
  hipMemsetAsync(bar, 0, 64, stream);

  k_transpose_qp<<<128, 256, 0, stream>>>(Wq, Wp,
      hws + HOFF_WQTH, hws + HOFF_WQTL, hws + HOFF_WPTH, hws + HOFF_WPTL);
  k_split_w<<<1024, 256, 0, stream>>>(gw, wih, whh,
      hws + HOFF_GWH, hws + HOFF_GWL, hws + HOFF_WIHH, hws + HOFF_WIHL,
      hws + HOFF_WHHH, hws + HOFF_WHHL);
  pe_main<<<NBLK, NTHR, 0, stream>>>(qin, pin, qmask, Ws, v, gb, bih, bhh, out, fws, hws, bar);
}

// Round 2
// 121492.615 us; speedup vs baseline: 3.5263x; 3.5263x over previous
//
#include <hip/hip_runtime.h>

// ---------------- problem constants ----------------
#define PL 400
#define QL 60
#define BB 128
#define EE 512
#define HH 256
#define DD 1024
#define G3 768
#define NBLK 256
#define NTHR 256
#define LDK 72   // padded K stride (shorts) for LDS tiles

typedef __attribute__((ext_vector_type(8))) short bfrag;
typedef __attribute__((ext_vector_type(4))) float facc;

// ---------------- bf16 helpers ----------------
__device__ __forceinline__ unsigned short f2bf(float x) {
  unsigned u = __float_as_uint(x);
  return (unsigned short)((u + 0x7fffu + ((u >> 16) & 1u)) >> 16);
}
__device__ __forceinline__ float bf2f(unsigned short h) {
  return __uint_as_float(((unsigned)h) << 16);
}
__device__ __forceinline__ void split_bf(float x, unsigned short& hi, unsigned short& lo) {
  hi = f2bf(x);
  lo = f2bf(x - bf2f(hi));
}
__device__ __forceinline__ float sigm(float x) { return 1.f / (1.f + __expf(-x)); }

// ---------------- ws layout (element offsets) ----------------
constexpr size_t SZ_QT  = (size_t)2 * QL * BB * HH;
constexpr size_t SZ_PT  = (size_t)2 * PL * BB * HH;
constexpr size_t SZ_H   = (size_t)2 * BB * HH;
constexpr size_t SZ_GP  = (size_t)4 * 2 * BB * DD;
constexpr size_t SZ_GIP = (size_t)4 * 2 * BB * G3;
constexpr size_t SZ_GHP = (size_t)2 * BB * G3;
constexpr size_t OFF_QT  = 0;
constexpr size_t OFF_PT  = OFF_QT + SZ_QT;
constexpr size_t OFF_H   = OFF_PT + SZ_PT;
constexpr size_t OFF_GP  = OFF_H + SZ_H;
constexpr size_t OFF_GIP = OFF_GP + SZ_GP;
constexpr size_t OFF_GHP = OFF_GIP + SZ_GIP;
constexpr size_t F32_TOT = OFF_GHP + SZ_GHP;
constexpr size_t HSZ_ATT = (size_t)2 * BB * EE;
constexpr size_t HSZ_WQT = (size_t)2 * HH * EE;
constexpr size_t HSZ_GW  = (size_t)2 * DD * DD;
constexpr size_t HSZ_WIH = (size_t)2 * G3 * DD;
constexpr size_t HSZ_WHH = (size_t)2 * G3 * HH;
constexpr size_t HOFF_ATTH = 0;
constexpr size_t HOFF_ATTL = HOFF_ATTH + HSZ_ATT;
constexpr size_t HOFF_WQTH = HOFF_ATTL + HSZ_ATT;
constexpr size_t HOFF_WQTL = HOFF_WQTH + HSZ_WQT;
constexpr size_t HOFF_WPTH = HOFF_WQTL + HSZ_WQT;
constexpr size_t HOFF_WPTL = HOFF_WPTH + HSZ_WQT;
constexpr size_t HOFF_GWH  = HOFF_WPTL + HSZ_WQT;
constexpr size_t HOFF_GWL  = HOFF_GWH + HSZ_GW;
constexpr size_t HOFF_WIHH = HOFF_GWL + HSZ_GW;
constexpr size_t HOFF_WIHL = HOFF_WIHH + HSZ_WIH;
constexpr size_t HOFF_WHHH = HOFF_WIHL + HSZ_WIH;
constexpr size_t HOFF_WHHL = HOFF_WHHH + HSZ_WHH;
constexpr size_t H_TOT     = HOFF_WHHL + HSZ_WHH;

// ---------------- grid barrier: slot-based, RMW-free, relaxed spins ----------------
// bar[0]           : go-flag (generation)
// bar[64 + i]      : arrival slot for block i (generation), own cache lines away from flag
// Release: ONE fence(release,agent) per block (wbl2) before slot store.
// Acquire: ONE fence(acquire,agent) per block (inv) after flag observed.
// No RMWs, no per-poll cache maintenance (relaxed agent loads = sc1 load only).
__device__ __forceinline__ void gbar(unsigned* bar, unsigned gen) {
  __syncthreads();
  if (threadIdx.x == 0) {
    __builtin_amdgcn_fence(__ATOMIC_RELEASE, "agent");
    __hip_atomic_store(&bar[64 + blockIdx.x], gen, __ATOMIC_RELAXED, __HIP_MEMORY_SCOPE_AGENT);
  }
  if (blockIdx.x == 0) {
    __syncthreads();
    if (threadIdx.x < 64) {
      for (int i = threadIdx.x; i < NBLK; i += 64) {
        unsigned sp = 0;
        while (__hip_atomic_load(&bar[64 + i], __ATOMIC_RELAXED, __HIP_MEMORY_SCOPE_AGENT) < gen) {
          __builtin_amdgcn_s_sleep(4);
          if (++sp > (1u << 26)) break;  // hang bailout
        }
      }
    }
    __syncthreads();
    if (threadIdx.x == 0) {
      __hip_atomic_store(&bar[0], gen, __ATOMIC_RELAXED, __HIP_MEMORY_SCOPE_AGENT);
    }
  }
  if (threadIdx.x == 0) {
    unsigned sp = 0;
    while (__hip_atomic_load(&bar[0], __ATOMIC_RELAXED, __HIP_MEMORY_SCOPE_AGENT) < gen) {
      __builtin_amdgcn_s_sleep(4);
      if (++sp > (1u << 26)) break;  // hang bailout
    }
    __builtin_amdgcn_fence(__ATOMIC_ACQUIRE, "agent");
  }
  __syncthreads();
}

// ---------------- 128x128 MFMA GEMM tile (hi/lo bf16 = fp32-accurate) ----------------
template <int AMODE>
__device__ void gemm128(unsigned short* sAh, unsigned short* sAl,
                        unsigned short* sBh, unsigned short* sBl,
                        const float* asrc, size_t astride,
                        const float* pin_t, const unsigned short* atth_d, const unsigned short* attl_d,
                        const float* gp, const float* gateb_d, int d,
                        const unsigned short* bh, const unsigned short* bl, size_t bstride,
                        float* dst, size_t dstride,
                        int kbase, int nchunks) {
  const int tid = threadIdx.x;
  const int lane = tid & 63;
  const int w = tid >> 6;
  const int wm = (w >> 1) << 6;
  const int wn = (w & 1) << 6;
  const int lr = lane & 15;
  const int lk = (lane >> 4) << 3;

  const facc fz = {0.f, 0.f, 0.f, 0.f};
  facc acc[4][4];
#pragma unroll
  for (int i = 0; i < 4; i++) {
#pragma unroll
    for (int j = 0; j < 4; j++) acc[i][j] = fz;
  }

  for (int kc = 0; kc < nchunks; ++kc) {
    const int kk0 = kbase + (kc << 6);
    for (int i = tid; i < 8192; i += NTHR) {
      const int r = i >> 6, k = i & 63;
      const int kk = kk0 + k;
      unsigned short uh, ul;
      if constexpr (AMODE == 0) {
        split_bf(asrc[(size_t)r * astride + kk], uh, ul);
      } else if constexpr (AMODE == 1) {
        if (kk < EE) {
          split_bf(pin_t[(size_t)r * EE + kk], uh, ul);
        } else {
          size_t o = (size_t)r * EE + (kk - EE);
          uh = atth_d[o]; ul = attl_d[o];
        }
      } else {
        float g = gp[((size_t)(0 + d) * BB + r) * DD + kk]
                + gp[((size_t)(2 + d) * BB + r) * DD + kk]
                + gp[((size_t)(4 + d) * BB + r) * DD + kk]
                + gp[((size_t)(6 + d) * BB + r) * DD + kk]
                + gateb_d[kk];
        float u;
        if (kk < EE) {
          u = pin_t[(size_t)r * EE + kk];
        } else {
          size_t o = (size_t)r * EE + (kk - EE);
          u = bf2f(atth_d[o]) + bf2f(attl_d[o]);
        }
        split_bf(u * sigm(g), uh, ul);
      }
      sAh[r * LDK + k] = uh;
      sAl[r * LDK + k] = ul;
      size_t bo = (size_t)r * bstride + kk;
      sBh[r * LDK + k] = bh[bo];
      sBl[r * LDK + k] = bl[bo];
    }
    __syncthreads();
#pragma unroll
    for (int k32 = 0; k32 < 64; k32 += 32) {
      bfrag ah[4], al_[4], bhf[4], blf[4];
#pragma unroll
      for (int f = 0; f < 4; f++) {
        const int ao = (wm + (f << 4) + lr) * LDK + k32 + lk;
        ah[f]  = *(const bfrag*)&sAh[ao];
        al_[f] = *(const bfrag*)&sAl[ao];
        const int bo2 = (wn + (f << 4) + lr) * LDK + k32 + lk;
        bhf[f] = *(const bfrag*)&sBh[bo2];
        blf[f] = *(const bfrag*)&sBl[bo2];
      }
#pragma unroll
      for (int i = 0; i < 4; i++) {
#pragma unroll
        for (int j = 0; j < 4; j++) {
          acc[i][j] = __builtin_amdgcn_mfma_f32_16x16x32_bf16(al_[i], bhf[j], acc[i][j], 0, 0, 0);
          acc[i][j] = __builtin_amdgcn_mfma_f32_16x16x32_bf16(ah[i],  blf[j], acc[i][j], 0, 0, 0);
          acc[i][j] = __builtin_amdgcn_mfma_f32_16x16x32_bf16(ah[i],  bhf[j], acc[i][j], 0, 0, 0);
        }
      }
    }
    __syncthreads();
  }
  const int orow = (lane >> 4) << 2;
  const int ocol = lane & 15;
#pragma unroll
  for (int i = 0; i < 4; i++) {
#pragma unroll
    for (int j = 0; j < 4; j++) {
#pragma unroll
      for (int q = 0; q < 4; q++) {
        dst[(size_t)(wm + (i << 4) + orow + q) * dstride + (wn + (j << 4) + ocol)] = acc[i][j][q];
      }
    }
  }
}

// ---------------- setup kernels ----------------
__global__ void __launch_bounds__(256) k_transpose_qp(
    const float* __restrict__ Wq, const float* __restrict__ Wp,
    unsigned short* __restrict__ wqth, unsigned short* __restrict__ wqtl,
    unsigned short* __restrict__ wpth, unsigned short* __restrict__ wptl) {
  __shared__ float tile[64 * 65];
  const int blk = blockIdx.x;
  const int mat = blk >> 6;
  const int rem = blk & 63;
  const int d = rem >> 5;
  const int rem2 = rem & 31;
  const int kt = rem2 >> 2;
  const int nt = rem2 & 3;
  const float* src = mat ? Wp : Wq;
  unsigned short* dh = mat ? wpth : wqth;
  unsigned short* dl = mat ? wptl : wqtl;
  const int tid = threadIdx.x;
  for (int i = tid; i < 4096; i += 256) {
    int kr = i >> 6, nc = i & 63;
    tile[kr * 65 + nc] = src[((size_t)d * EE + kt * 64 + kr) * HH + nt * 64 + nc];
  }
  __syncthreads();
  for (int i = tid; i < 4096; i += 256) {
    int n = i >> 6, k = i & 63;
    unsigned short hi, lo;
    split_bf(tile[k * 65 + n], hi, lo);
    size_t o = ((size_t)d * HH + nt * 64 + n) * EE + kt * 64 + k;
    dh[o] = hi; dl[o] = lo;
  }
}

__global__ void __launch_bounds__(256) k_split_w(
    const float* __restrict__ gw, const float* __restrict__ wih, const float* __restrict__ whh,
    unsigned short* __restrict__ gwh, unsigned short* __restrict__ gwl,
    unsigned short* __restrict__ wihh, unsigned short* __restrict__ wihl,
    unsigned short* __restrict__ whhh, unsigned short* __restrict__ whhl) {
  const size_t N1 = HSZ_GW, N2 = HSZ_WIH, N3 = HSZ_WHH;
  for (size_t i = (size_t)blockIdx.x * 256 + threadIdx.x; i < N1 + N2 + N3;
       i += (size_t)gridDim.x * 256) {
    float x; unsigned short *ph, *pl; size_t o;
    if (i < N1)           { o = i;           x = gw[o];  ph = gwh;  pl = gwl; }
    else if (i < N1 + N2) { o = i - N1;      x = wih[o]; ph = wihh; pl = wihl; }
    else                  { o = i - N1 - N2; x = whh[o]; ph = whhh; pl = whhl; }
    unsigned short hi, lo;
    split_bf(x, hi, lo);
    ph[o] = hi; pl[o] = lo;
  }
}

// ---------------- the persistent kernel ----------------
__global__ void __launch_bounds__(NTHR, 1) pe_main(
    const float* __restrict__ qin, const float* __restrict__ pin,
    const unsigned char* __restrict__ qmask,
    const float* __restrict__ Ws, const float* __restrict__ vvec,
    const float* __restrict__ gateb,
    const float* __restrict__ bih, const float* __restrict__ bhh,
    float* __restrict__ out,
    float* __restrict__ fws, unsigned short* __restrict__ hws,
    unsigned* __restrict__ bar) {
  __shared__ __align__(16) unsigned char smem_raw[73728];
  unsigned short* sAh = (unsigned short*)smem_raw;
  unsigned short* sAl = sAh + 128 * LDK;
  unsigned short* sBh = sAl + 128 * LDK;
  unsigned short* sBl = sBh + 128 * LDK;
  float* fsm = (float*)smem_raw;

  float* qt   = fws + OFF_QT;
  float* pt   = fws + OFF_PT;
  float* hbuf = fws + OFF_H;
  float* gp   = fws + OFF_GP;
  float* gip  = fws + OFF_GIP;
  float* ghp  = fws + OFF_GHP;
  unsigned short* atth = hws + HOFF_ATTH;
  unsigned short* attl = hws + HOFF_ATTL;
  unsigned short* wqth = hws + HOFF_WQTH;
  unsigned short* wqtl = hws + HOFF_WQTL;
  unsigned short* wpth = hws + HOFF_WPTH;
  unsigned short* wptl = hws + HOFF_WPTL;
  unsigned short* gwh  = hws + HOFF_GWH;
  unsigned short* gwl  = hws + HOFF_GWL;
  unsigned short* wihh = hws + HOFF_WIHH;
  unsigned short* wihl = hws + HOFF_WIHL;
  unsigned short* whhh = hws + HOFF_WHHH;
  unsigned short* whhl = hws + HOFF_WHHL;

  const int blk = blockIdx.x;
  const int tid = threadIdx.x;
  unsigned bt = 0;

  // ---- prologue: q_temp / p_temp GEMMs ----
  for (int tt = blk; tt < 1840; tt += NBLK) {
    if (tt < 1600) {
      int d = tt / 800, rem = tt % 800, mt = rem >> 1, nt = rem & 1;
      gemm128<0>(sAh, sAl, sBh, sBl,
                 pin + (size_t)mt * BB * EE, (size_t)EE,
                 nullptr, nullptr, nullptr, nullptr, nullptr, 0,
                 wpth + ((size_t)d * HH + (size_t)nt * 128) * EE,
                 wptl + ((size_t)d * HH + (size_t)nt * 128) * EE, (size_t)EE,
                 pt + ((size_t)d * PL * BB + (size_t)mt * BB) * HH + nt * 128, (size_t)HH,
                 0, 8);
    } else {
      int u2 = tt - 1600;
      int d = u2 / 120, rem = u2 % 120, mt = rem >> 1, nt = rem & 1;
      gemm128<0>(sAh, sAl, sBh, sBl,
                 qin + (size_t)mt * BB * EE, (size_t)EE,
                 nullptr, nullptr, nullptr, nullptr, nullptr, 0,
                 wqth + ((size_t)d * HH + (size_t)nt * 128) * EE,
                 wqtl + ((size_t)d * HH + (size_t)nt * 128) * EE, (size_t)EE,
                 qt + ((size_t)d * QL * BB + (size_t)mt * BB) * HH + nt * 128, (size_t)HH,
                 0, 8);
    }
  }
  gbar(bar, ++bt);

  const int d_ab = blk >> 7, b_ab = blk & 127;
  float stv = 0.f;

  for (int s = 0; s < PL; ++s) {
    // ---------- phase A: attention ----------
    {
      const int d = d_ab, b = b_ab;
      const int t = d ? (PL - 1 - s) : s;
      float* sm = fsm;
      float* sv = fsm + 256;
      float* slog = fsm + 512;
      float* swgt = fsm + 576;
      sm[tid] = stv + pt[(((size_t)d * PL + t) * BB + b) * HH + tid];
      sv[tid] = vvec[d * HH + tid];
      __syncthreads();
      const int w = tid >> 6, lane = tid & 63;
      for (int q = w; q < QL; q += 4) {
        float a = 0.f;
#pragma unroll
        for (int jj = 0; jj < 4; jj++) {
          int j = lane + jj * 64;
          float qv = qt[(((size_t)d * QL + q) * BB + b) * HH + j];
          a += tanhf(qv + sm[j]) * sv[j];
        }
        for (int off = 32; off; off >>= 1) a += __shfl_down(a, off, 64);
        if (lane == 0) slog[q] = a;
      }
      __syncthreads();
      if (w == 0) {
        float x = -3.0e38f;
        if (lane < QL) {
          x = slog[lane];
          if (qmask[lane * BB + b]) x = -3.0e38f;
        }
        float mx = x;
        for (int off = 32; off; off >>= 1) mx = fmaxf(mx, __shfl_xor(mx, off, 64));
        float e = (lane < QL) ? __expf(x - mx) : 0.f;
        float sum2 = e;
        for (int off = 32; off; off >>= 1) sum2 += __shfl_xor(sum2, off, 64);
        if (lane < QL) swgt[lane] = e / sum2;
      }
      __syncthreads();
#pragma unroll
      for (int cc = 0; cc < 2; cc++) {
        int c = tid + cc * 256;
        float a = 0.f;
        for (int q = 0; q < QL; q++) a += swgt[q] * qin[((size_t)q * BB + b) * EE + c];
        unsigned short hi, lo;
        split_bf(a, hi, lo);
        atth[((size_t)d * BB + b) * EE + c] = hi;
        attl[((size_t)d * BB + b) * EE + c] = lo;
      }
    }
    gbar(bar, ++bt);

    // ---------- phase B: gate GEMM partials (k-split 4) + gh (blocks 64-75) ----------
    if (blk < 64) {
      const int d = blk >> 5, r5 = blk & 31, nt = r5 >> 2, ks = r5 & 3;
      const int t = d ? (PL - 1 - s) : s;
      gemm128<1>(sAh, sAl, sBh, sBl,
                 nullptr, 0,
                 pin + (size_t)t * BB * EE, atth + (size_t)d * BB * EE, attl + (size_t)d * BB * EE,
                 nullptr, nullptr, d,
                 gwh + ((size_t)d * DD + (size_t)nt * 128) * DD,
                 gwl + ((size_t)d * DD + (size_t)nt * 128) * DD, (size_t)DD,
                 gp + ((size_t)(ks * 2 + d) * BB) * DD + nt * 128, (size_t)DD,
                 ks * 256, 4);
    } else if (blk < 76) {
      const int m = blk - 64, d = m / 6, nt = m % 6;
      gemm128<0>(sAh, sAl, sBh, sBl,
                 hbuf + (size_t)d * BB * HH, (size_t)HH,
                 nullptr, nullptr, nullptr, nullptr, nullptr, 0,
                 whhh + ((size_t)d * G3 + (size_t)nt * 128) * HH,
                 whhl + ((size_t)d * G3 + (size_t)nt * 128) * HH, (size_t)HH,
                 ghp + ((size_t)d * BB) * G3 + nt * 128, (size_t)G3,
                 0, 4);
    }
    gbar(bar, ++bt);

    // ---------- phase C1: gi partials (x gated inline) ----------
    if (blk < 48) {
      const int d = blk / 24, rem = blk % 24, nt = rem >> 2, ks = rem & 3;
      const int t = d ? (PL - 1 - s) : s;
      gemm128<2>(sAh, sAl, sBh, sBl,
                 nullptr, 0,
                 pin + (size_t)t * BB * EE, atth + (size_t)d * BB * EE, attl + (size_t)d * BB * EE,
                 gp, gateb + (size_t)d * DD, d,
                 wihh + ((size_t)d * G3 + (size_t)nt * 128) * DD,
                 wihl + ((size_t)d * G3 + (size_t)nt * 128) * DD, (size_t)DD,
                 gip + ((size_t)(ks * 2 + d) * BB) * G3 + nt * 128, (size_t)G3,
                 ks * 256, 4);
    }
    gbar(bar, ++bt);

    // ---------- phase C2: GRU elementwise + output + next state_temp ----------
    {
      const int d = d_ab, b = b_ab, j = tid;
      const int t = d ? (PL - 1 - s) : s;
      const size_t rb = (size_t)d * BB + b;
      float hp = hbuf[rb * HH + j];
      float gi0 = 0.f, gi1 = 0.f, gi2 = 0.f;
#pragma unroll
      for (int k2 = 0; k2 < 4; k2++) {
        size_t ro = ((size_t)(k2 * 2 + d) * BB + b) * G3;
        gi0 += gip[ro + j];
        gi1 += gip[ro + HH + j];
        gi2 += gip[ro + 2 * HH + j];
      }
      gi0 += bih[(size_t)d * G3 + j];
      gi1 += bih[(size_t)d * G3 + HH + j];
      gi2 += bih[(size_t)d * G3 + 2 * HH + j];
      size_t go = rb * G3;
      float gh0 = ghp[go + j] + bhh[(size_t)d * G3 + j];
      float gh1 = ghp[go + HH + j] + bhh[(size_t)d * G3 + HH + j];
      float gh2 = ghp[go + 2 * HH + j] + bhh[(size_t)d * G3 + 2 * HH + j];
      float r = sigm(gi0 + gh0);
      float z = sigm(gi1 + gh1);
      float n = tanhf(gi2 + r * gh2);
      float hn = (1.f - z) * n + z * hp;
      hbuf[rb * HH + j] = hn;
      out[((size_t)t * BB + b) * 512 + d * HH + j] = hn;
      float* hrow = fsm;
      hrow[j] = hn;
      __syncthreads();
      const float* Wsd = Ws + (size_t)d * HH * HH;
      float a2 = 0.f;
      for (int k = 0; k < HH; k += 4) {
        float4 h4 = *(const float4*)&hrow[k];
        a2 += h4.x * Wsd[(size_t)(k + 0) * HH + j] + h4.y * Wsd[(size_t)(k + 1) * HH + j]
            + h4.z * Wsd[(size_t)(k + 2) * HH + j] + h4.w * Wsd[(size_t)(k + 3) * HH + j];
      }
      stv = a2;
      __syncthreads();
    }
    // no barrier needed C2 -> A (A only uses intra-block data + static tensors)
  }
}

// ---------------- launch ----------------
extern "C" void kernel_launch(void* const* d_in, const int* in_sizes, int n_in,
                              void* d_out, int out_size, void* d_ws, size_t ws_size,
                              hipStream_t stream) {
  const float* qin = (const float*)d_in[0];
  const float* pin = (const float*)d_in[1];
  const unsigned char* qmask = (const unsigned char*)d_in[2];
  const float* Wq  = (const float*)d_in[3];
  const float* Wp  = (const float*)d_in[4];
  const float* Ws  = (const float*)d_in[5];
  const float* v   = (const float*)d_in[6];
  const float* gw  = (const float*)d_in[7];
  const float* gb  = (const float*)d_in[8];
  const float* wih = (const float*)d_in[9];
  const float* whh = (const float*)d_in[10];
  const float* bih = (const float*)d_in[11];
  const float* bhh = (const float*)d_in[12];
  float* out = (float*)d_out;

  float* fws = (float*)d_ws;
  unsigned short* hws = (unsigned short*)((char*)d_ws + F32_TOT * sizeof(float));
  unsigned* bar = (unsigned*)((char*)d_ws + F32_TOT * sizeof(float) + H_TOT * sizeof(unsigned short));
  size_t need = F32_TOT * sizeof(float) + H_TOT * sizeof(unsigned short) + 4096;
  if (ws_size < need) return;

  // zero the GRU state and the barrier slots/flag (every call — replay-safe)
  hipMemsetAsync((char*)d_ws + OFF_H * sizeof(float), 0, SZ_H * sizeof(float), stream);
  hipMemsetAsync(bar, 0, 2048, stream);

  k_transpose_qp<<<128, 256, 0, stream>>>(Wq, Wp,
      hws + HOFF_WQTH, hws + HOFF_WQTL, hws + HOFF_WPTH, hws + HOFF_WPTL);
  k_split_w<<<1024, 256, 0, stream>>>(gw, wih, whh,
      hws + HOFF_GWH, hws + HOFF_GWL, hws + HOFF_WIHH, hws + HOFF_WIHL,
      hws + HOFF_WHHH, hws + HOFF_WHHL);
  pe_main<<<NBLK, NTHR, 0, stream>>>(qin, pin, qmask, Ws, v, gb, bih, bhh, out, fws, hws, bar);
}

// Round 3
// 47706.137 us; speedup vs baseline: 8.9804x; 2.5467x over previous
//
#include <hip/hip_runtime.h>

// ---------------- problem constants ----------------
#define PL 400
#define QL 60
#define BB 128
#define EE 512
#define HH 256
#define DD 1024
#define G3 768
#define NBLK 256
#define NTHR 512
#define LDK 72   // padded K stride (shorts) for LDS tiles

typedef __attribute__((ext_vector_type(8))) short bfrag;
typedef __attribute__((ext_vector_type(4))) float facc;

// ---------------- bf16 helpers ----------------
__device__ __forceinline__ unsigned short f2bf(float x) {
  unsigned u = __float_as_uint(x);
  return (unsigned short)((u + 0x7fffu + ((u >> 16) & 1u)) >> 16);
}
__device__ __forceinline__ float bf2f(unsigned short h) {
  return __uint_as_float(((unsigned)h) << 16);
}
__device__ __forceinline__ void split_bf(float x, unsigned short& hi, unsigned short& lo) {
  hi = f2bf(x);
  lo = f2bf(x - bf2f(hi));
}
__device__ __forceinline__ float sigm(float x) { return 1.f / (1.f + __expf(-x)); }

__device__ __forceinline__ float ald(const float* p) {
  return __hip_atomic_load((float*)p, __ATOMIC_RELAXED, __HIP_MEMORY_SCOPE_AGENT);
}
__device__ __forceinline__ void ast(float* p, float v) {
  __hip_atomic_store(p, v, __ATOMIC_RELAXED, __HIP_MEMORY_SCOPE_AGENT);
}
__device__ __forceinline__ unsigned aldu(const unsigned* p) {
  return __hip_atomic_load((unsigned*)p, __ATOMIC_RELAXED, __HIP_MEMORY_SCOPE_AGENT);
}
__device__ __forceinline__ void astu(unsigned* p, unsigned v) {
  __hip_atomic_store(p, v, __ATOMIC_RELAXED, __HIP_MEMORY_SCOPE_AGENT);
}

// ---------------- ws layout (element offsets) ----------------
constexpr size_t SZ_QT  = (size_t)2 * QL * BB * HH;
constexpr size_t SZ_PT  = (size_t)2 * PL * BB * HH;
constexpr size_t SZ_H   = (size_t)2 * BB * HH;
constexpr size_t SZ_GP  = (size_t)4 * 2 * BB * DD;   // gate partials (k-split 4)
constexpr size_t SZ_GIP = (size_t)4 * 2 * BB * G3;   // gi partials (k-split 4)
constexpr size_t SZ_GHP = (size_t)2 * BB * G3;       // gh (k-complete)
constexpr size_t SZ_WST = (size_t)2 * HH * HH;       // Ws transposed fp32
constexpr size_t OFF_QT  = 0;
constexpr size_t OFF_PT  = OFF_QT + SZ_QT;
constexpr size_t OFF_H   = OFF_PT + SZ_PT;
constexpr size_t OFF_GP  = OFF_H + SZ_H;
constexpr size_t OFF_GIP = OFF_GP + SZ_GP;
constexpr size_t OFF_GHP = OFF_GIP + SZ_GIP;
constexpr size_t OFF_WST = OFF_GHP + SZ_GHP;
constexpr size_t F32_TOT = OFF_WST + SZ_WST;
// bf16 (ushort) region
constexpr size_t HSZ_ATT = (size_t)2 * BB * EE;      // (x2 regions reused as uint attp)
constexpr size_t HSZ_WQT = (size_t)2 * HH * EE;
constexpr size_t HSZ_GW  = (size_t)2 * DD * DD;
constexpr size_t HSZ_WIH = (size_t)2 * G3 * DD;
constexpr size_t HSZ_WHH = (size_t)2 * G3 * HH;
constexpr size_t HOFF_ATTP = 0;                      // uint region: 2*BB*EE uints == 2*HSZ_ATT shorts
constexpr size_t HOFF_WQTH = HOFF_ATTP + 2 * HSZ_ATT;
constexpr size_t HOFF_WQTL = HOFF_WQTH + HSZ_WQT;
constexpr size_t HOFF_WPTH = HOFF_WQTL + HSZ_WQT;
constexpr size_t HOFF_WPTL = HOFF_WPTH + HSZ_WQT;
constexpr size_t HOFF_GWH  = HOFF_WPTL + HSZ_WQT;
constexpr size_t HOFF_GWL  = HOFF_GWH + HSZ_GW;
constexpr size_t HOFF_WIHH = HOFF_GWL + HSZ_GW;
constexpr size_t HOFF_WIHL = HOFF_WIHH + HSZ_WIH;
constexpr size_t HOFF_WHHH = HOFF_WIHL + HSZ_WIH;
constexpr size_t HOFF_WHHL = HOFF_WHHH + HSZ_WHH;
constexpr size_t H_TOT     = HOFF_WHHL + HSZ_WHH;

// ---------------- grid barrier: flat all-poll, fence-free ----------------
// Data protocol is agent-scope relaxed atomics (coherent at MALL); the
// compiler-emitted s_waitcnt vmcnt(0) before s_barrier drains each wave's
// stores, so slot-store-after-__syncthreads is a valid release point.
__device__ __forceinline__ void gbar(unsigned* slots, unsigned gen) {
  asm volatile("" ::: "memory");
  __syncthreads();  // drains vmcnt for all waves of this block
  if (threadIdx.x == 0)
    __hip_atomic_store(&slots[blockIdx.x], gen, __ATOMIC_RELAXED, __HIP_MEMORY_SCOPE_AGENT);
  if (threadIdx.x < NBLK) {
    unsigned sp = 0;
    while (__hip_atomic_load(&slots[threadIdx.x], __ATOMIC_RELAXED, __HIP_MEMORY_SCOPE_AGENT) < gen) {
      __builtin_amdgcn_s_sleep(1);
      if (++sp > (1u << 26)) break;  // hang bailout
    }
  }
  __syncthreads();
  asm volatile("" ::: "memory");
}

// ---------------- unified MFMA GEMM tile ----------------
// M always 128 (batch). NT = 128 or 64. K per call = nch*64 (kbase offset).
// AMODE 0: A = fp32 plain (asrc/astride)           [prologue]
// AMODE 3: A = fp32 via agent-atomic loads          [gh: hbuf]
// AMODE 1: A = u = [pin_t | att]                    [gate]
// AMODE 2: A = x = u * sigm(sum4 gp + gate_b)       [gi]
// BSPLIT: B hi/lo (3 MFMA) vs single (2 MFMA). A is always hi/lo.
// BGLOBAL: stage B from global per chunk (prologue) vs LDS-resident (4 chunks).
// OATOMIC: C written via agent-atomic stores.
template <int NT, int AMODE, bool BSPLIT, bool BGLOBAL, bool OATOMIC>
__device__ void gemm_t(unsigned short* sAh, unsigned short* sAl, unsigned short* warea,
                       const float* asrc, int astride,
                       const float* pin_t, const unsigned* attp_d,
                       const float* gp, const float* gateb_d, int dsel,
                       const unsigned short* bh_g, const unsigned short* bl_g, int bstride,
                       float* dst, int dstride,
                       int kbase, int nch) {
  const int tid = threadIdx.x;
  const int lane = tid & 63;
  const int w = tid >> 6;
  constexpr int FM = (NT == 128) ? 4 : 2;
  constexpr int FN = 2;
  const int wm = (NT == 128) ? ((w >> 2) << 6) : ((w >> 1) << 5);
  const int wn = (NT == 128) ? ((w & 3) << 5) : ((w & 1) << 5);
  const int lr = lane & 15;
  const int lk = (lane >> 4) << 3;

  unsigned short* wh = warea;
  unsigned short* wl = BGLOBAL ? (warea + 9216) : (warea + 4 * NT * LDK);

  const facc fz = {0.f, 0.f, 0.f, 0.f};
  facc acc[FM][FN];
#pragma unroll
  for (int i = 0; i < FM; i++)
#pragma unroll
    for (int j = 0; j < FN; j++) acc[i][j] = fz;

  for (int ch = 0; ch < nch; ++ch) {
    // ---- stage A (128 x 64) as hi/lo ----
    for (int i = tid; i < 8192; i += NTHR) {
      const int r = i >> 6, k = i & 63;
      const int kk = kbase + (ch << 6) + k;
      unsigned short uh, ul;
      if constexpr (AMODE == 0) {
        split_bf(asrc[(size_t)r * astride + kk], uh, ul);
      } else if constexpr (AMODE == 3) {
        split_bf(ald(&asrc[(size_t)r * astride + kk]), uh, ul);
      } else if constexpr (AMODE == 1) {
        if (kk < EE) {
          split_bf(pin_t[(size_t)r * EE + kk], uh, ul);
        } else {
          unsigned p = aldu(&attp_d[(size_t)r * EE + kk - EE]);
          uh = (unsigned short)(p >> 16);
          ul = (unsigned short)p;
        }
      } else {  // AMODE 2
        float g = gateb_d[kk];
#pragma unroll
        for (int ks2 = 0; ks2 < 4; ks2++)
          g += ald(&gp[((size_t)(dsel * 4 + ks2) * BB + r) * DD + kk]);
        float u;
        if (kk < EE) {
          u = pin_t[(size_t)r * EE + kk];
        } else {
          unsigned p = aldu(&attp_d[(size_t)r * EE + kk - EE]);
          u = bf2f((unsigned short)(p >> 16)) + bf2f((unsigned short)p);
        }
        split_bf(u * sigm(g), uh, ul);
      }
      sAh[r * LDK + k] = uh;
      sAl[r * LDK + k] = ul;
    }
    // ---- stage B from global (prologue only) ----
    if constexpr (BGLOBAL) {
      for (int i = tid; i < 8192; i += NTHR) {
        const int r = i >> 6, k = i & 63;
        const int kk = kbase + (ch << 6) + k;
        wh[r * LDK + k] = bh_g[(size_t)r * bstride + kk];
        wl[r * LDK + k] = bl_g[(size_t)r * bstride + kk];
      }
    }
    __syncthreads();
    const int wch = BGLOBAL ? 0 : ch;
#pragma unroll
    for (int k32 = 0; k32 < 64; k32 += 32) {
      bfrag ah[FM], al_[FM], bhf[FN], blf[FN];
#pragma unroll
      for (int f = 0; f < FM; f++) {
        const int ao = (wm + (f << 4) + lr) * LDK + k32 + lk;
        ah[f]  = *(const bfrag*)&sAh[ao];
        al_[f] = *(const bfrag*)&sAl[ao];
      }
#pragma unroll
      for (int f = 0; f < FN; f++) {
        const int bo = (wch * NT + wn + (f << 4) + lr) * LDK + k32 + lk;
        bhf[f] = *(const bfrag*)&wh[bo];
        if constexpr (BSPLIT) blf[f] = *(const bfrag*)&wl[bo];
      }
#pragma unroll
      for (int i = 0; i < FM; i++)
#pragma unroll
        for (int j = 0; j < FN; j++) {
          acc[i][j] = __builtin_amdgcn_mfma_f32_16x16x32_bf16(al_[i], bhf[j], acc[i][j], 0, 0, 0);
          if constexpr (BSPLIT)
            acc[i][j] = __builtin_amdgcn_mfma_f32_16x16x32_bf16(ah[i], blf[j], acc[i][j], 0, 0, 0);
          acc[i][j] = __builtin_amdgcn_mfma_f32_16x16x32_bf16(ah[i], bhf[j], acc[i][j], 0, 0, 0);
        }
    }
    __syncthreads();
  }
  const int orow = (lane >> 4) << 2;
  const int ocol = lane & 15;
#pragma unroll
  for (int i = 0; i < FM; i++)
#pragma unroll
    for (int j = 0; j < FN; j++)
#pragma unroll
      for (int q = 0; q < 4; q++) {
        float* p = &dst[(size_t)(wm + (i << 4) + orow + q) * dstride + (wn + (j << 4) + ocol)];
        if constexpr (OATOMIC) ast(p, acc[i][j][q]);
        else *p = acc[i][j][q];
      }
}

// ---------------- setup kernels ----------------
__global__ void __launch_bounds__(256) k_transpose_qp(
    const float* __restrict__ Wq, const float* __restrict__ Wp,
    unsigned short* __restrict__ wqth, unsigned short* __restrict__ wqtl,
    unsigned short* __restrict__ wpth, unsigned short* __restrict__ wptl) {
  __shared__ float tile[64 * 65];
  const int blk = blockIdx.x;
  const int mat = blk >> 6;
  const int rem = blk & 63;
  const int d = rem >> 5;
  const int rem2 = rem & 31;
  const int kt = rem2 >> 2;
  const int nt = rem2 & 3;
  const float* src = mat ? Wp : Wq;
  unsigned short* dh = mat ? wpth : wqth;
  unsigned short* dl = mat ? wptl : wqtl;
  const int tid = threadIdx.x;
  for (int i = tid; i < 4096; i += 256) {
    int kr = i >> 6, nc = i & 63;
    tile[kr * 65 + nc] = src[((size_t)d * EE + kt * 64 + kr) * HH + nt * 64 + nc];
  }
  __syncthreads();
  for (int i = tid; i < 4096; i += 256) {
    int n = i >> 6, k = i & 63;
    unsigned short hi, lo;
    split_bf(tile[k * 65 + n], hi, lo);
    size_t o = ((size_t)d * HH + nt * 64 + n) * EE + kt * 64 + k;
    dh[o] = hi; dl[o] = lo;
  }
}

__global__ void __launch_bounds__(256) k_split_w(
    const float* __restrict__ gw, const float* __restrict__ wih, const float* __restrict__ whh,
    unsigned short* __restrict__ gwh, unsigned short* __restrict__ gwl,
    unsigned short* __restrict__ wihh, unsigned short* __restrict__ wihl,
    unsigned short* __restrict__ whhh, unsigned short* __restrict__ whhl) {
  const size_t N1 = HSZ_GW, N2 = HSZ_WIH, N3 = HSZ_WHH;
  for (size_t i = (size_t)blockIdx.x * 256 + threadIdx.x; i < N1 + N2 + N3;
       i += (size_t)gridDim.x * 256) {
    float x; unsigned short *ph, *pl; size_t o;
    if (i < N1)           { o = i;           x = gw[o];  ph = gwh;  pl = gwl; }
    else if (i < N1 + N2) { o = i - N1;      x = wih[o]; ph = wihh; pl = wihl; }
    else                  { o = i - N1 - N2; x = whh[o]; ph = whhh; pl = whhl; }
    unsigned short hi, lo;
    split_bf(x, hi, lo);
    ph[o] = hi; pl[o] = lo;
  }
}

__global__ void __launch_bounds__(256) k_wst(const float* __restrict__ Ws,
                                             float* __restrict__ wst) {
  // WsT[d][j][k] = Ws[d][k][j]
  size_t i = (size_t)blockIdx.x * 256 + threadIdx.x;
  if (i >= SZ_WST) return;
  int d = (int)(i >> 16);
  int j = (int)((i >> 8) & 255);
  int k = (int)(i & 255);
  wst[i] = Ws[((size_t)d * HH + k) * HH + j];
}

// ---------------- the persistent kernel ----------------
__global__ void __launch_bounds__(NTHR, 1) pe_main(
    const float* __restrict__ qin, const float* __restrict__ pin,
    const unsigned char* __restrict__ qmask,
    const float* __restrict__ vvec, const float* __restrict__ gateb,
    const float* __restrict__ bih, const float* __restrict__ bhh,
    float* __restrict__ out,
    float* __restrict__ fws, unsigned short* __restrict__ hws,
    unsigned* __restrict__ bar) {
  __shared__ __align__(16) unsigned short smem[55296];  // 110.6 KB
  unsigned short* sAh = smem;            // 9216 shorts
  unsigned short* sAl = smem + 9216;     // 9216 shorts
  unsigned short* warea = smem + 18432;  // 36864 shorts (weight tile / prologue B-staging)
  float* fsm = (float*)smem;             // scratch for phases A & C2 (inside sAh/sAl area)

  float* qt   = fws + OFF_QT;
  float* pt   = fws + OFF_PT;
  float* hbuf = fws + OFF_H;
  float* gp   = fws + OFF_GP;
  float* gip  = fws + OFF_GIP;
  float* ghp  = fws + OFF_GHP;
  float* wst  = fws + OFF_WST;
  unsigned* attp = (unsigned*)(hws + HOFF_ATTP);
  unsigned short* wqth = hws + HOFF_WQTH;
  unsigned short* wqtl = hws + HOFF_WQTL;
  unsigned short* wpth = hws + HOFF_WPTH;
  unsigned short* wptl = hws + HOFF_WPTL;
  unsigned short* gwh  = hws + HOFF_GWH;
  unsigned short* wihh = hws + HOFF_WIHH;
  unsigned short* wihl = hws + HOFF_WIHL;
  unsigned short* whhh = hws + HOFF_WHHH;
  unsigned short* whhl = hws + HOFF_WHHL;

  const int blk = blockIdx.x;
  const int tid = threadIdx.x;
  const int lane = tid & 63;
  const int w = tid >> 6;
  unsigned gen = 0;

  // ---- prologue: q_temp / p_temp GEMMs (uses warea as B staging) ----
  for (int tt = blk; tt < 1840; tt += NBLK) {
    if (tt < 1600) {
      int d = tt / 800, rem = tt % 800, mt = rem >> 1, ntp = rem & 1;
      gemm_t<128, 0, true, true, false>(sAh, sAl, warea,
          pin + (size_t)mt * BB * EE, EE,
          nullptr, nullptr, nullptr, nullptr, 0,
          wpth + ((size_t)d * HH + ntp * 128) * EE,
          wptl + ((size_t)d * HH + ntp * 128) * EE, EE,
          pt + ((size_t)d * PL * BB + (size_t)mt * BB) * HH + ntp * 128, HH, 0, 8);
    } else {
      int u2 = tt - 1600;
      int d = u2 / 120, rem = u2 % 120, mt = rem >> 1, ntp = rem & 1;
      gemm_t<128, 0, true, true, false>(sAh, sAl, warea,
          qin + (size_t)mt * BB * EE, EE,
          nullptr, nullptr, nullptr, nullptr, 0,
          wqth + ((size_t)d * HH + ntp * 128) * EE,
          wqtl + ((size_t)d * HH + ntp * 128) * EE, EE,
          qt + ((size_t)d * QL * BB + (size_t)mt * BB) * HH + ntp * 128, HH, 0, 8);
    }
  }

  // ---- prologue: load this block's resident weight tile into LDS ----
  if (blk < 64) {               // gate: W single-bf16, N=128, K=256
    const int d = blk >> 5, r5 = blk & 31, nt = r5 >> 2, ks = r5 & 3;
    const unsigned short* src = gwh + (size_t)(d * DD + nt * 128) * DD + ks * 256;
    for (int i = tid; i < 32768; i += NTHR) {
      int ch = i >> 13, n = (i >> 6) & 127, k = i & 63;
      warea[(ch * 128 + n) * LDK + k] = src[(size_t)n * DD + ch * 64 + k];
    }
  } else if (blk < 160) {       // gi: W hi/lo, N=64, K=256
    const int g = blk - 64, d = g / 48, r = g % 48, nt = r >> 2, ks = r & 3;
    const unsigned short* sh = wihh + (size_t)(d * G3 + nt * 64) * DD + ks * 256;
    const unsigned short* sl = wihl + (size_t)(d * G3 + nt * 64) * DD + ks * 256;
    for (int i = tid; i < 16384; i += NTHR) {
      int ch = i >> 12, n = (i >> 6) & 63, k = i & 63;
      warea[(ch * 64 + n) * LDK + k]         = sh[(size_t)n * DD + ch * 64 + k];
      warea[18432 + (ch * 64 + n) * LDK + k] = sl[(size_t)n * DD + ch * 64 + k];
    }
  } else if (blk < 184) {       // gh: W hi/lo, N=64, K=256
    const int g = blk - 160, d = g / 12, nt = g % 12;
    const unsigned short* sh = whhh + (size_t)(d * G3 + nt * 64) * HH;
    const unsigned short* sl = whhl + (size_t)(d * G3 + nt * 64) * HH;
    for (int i = tid; i < 16384; i += NTHR) {
      int ch = i >> 12, n = (i >> 6) & 63, k = i & 63;
      warea[(ch * 64 + n) * LDK + k]         = sh[(size_t)n * HH + ch * 64 + k];
      warea[18432 + (ch * 64 + n) * LDK + k] = sl[(size_t)n * HH + ch * 64 + k];
    }
  }

  // publish qt/pt (plain stores) once; per-step data uses atomics only.
  __builtin_amdgcn_fence(__ATOMIC_RELEASE, "agent");
  gbar(bar, ++gen);

  // init per-(d,b) local state
  float* sm = fsm;            // 256
  float* sv = fsm + 256;      // 256
  float* slog = fsm + 512;    // 64
  float* swgt = fsm + 576;    // 64
  float* sstv = fsm + 640;    // 256 (state_temp, persists C2 -> A)
  float* spart = fsm + 896;   // 512
  float* hrow = fsm + 1408;   // 256
  if (tid < 256) sstv[tid] = 0.f;
  __syncthreads();

  const int d_ab = blk >> 7, b_ab = blk & 127;
  float hreg = 0.f;  // h[j=tid&255] for this (d,b)

  for (int s = 0; s < PL; ++s) {
    // ---------- phase A: attention (all blocks; one (d,b) each) ----------
    {
      const int d = d_ab, b = b_ab;
      const int t = d ? (PL - 1 - s) : s;
      if (tid < 256) {
        sm[tid] = sstv[tid] + pt[(((size_t)d * PL + t) * BB + b) * HH + tid];
        sv[tid] = vvec[d * HH + tid];
      }
      __syncthreads();
      for (int q = w; q < QL; q += 8) {
        float a = 0.f;
#pragma unroll
        for (int jj = 0; jj < 4; jj++) {
          int j = lane + jj * 64;
          a += tanhf(qt[(((size_t)d * QL + q) * BB + b) * HH + j] + sm[j]) * sv[j];
        }
        for (int off = 32; off; off >>= 1) a += __shfl_down(a, off, 64);
        if (lane == 0) slog[q] = a;
      }
      __syncthreads();
      if (tid < 64) {
        float x = -3.0e38f;
        if (lane < QL) {
          x = slog[lane];
          if (qmask[lane * BB + b]) x = -3.0e38f;
        }
        float mx = x;
        for (int off = 32; off; off >>= 1) mx = fmaxf(mx, __shfl_xor(mx, off, 64));
        float e = (lane < QL) ? __expf(x - mx) : 0.f;
        float sum2 = e;
        for (int off = 32; off; off >>= 1) sum2 += __shfl_xor(sum2, off, 64);
        if (lane < QL) swgt[lane] = e / sum2;
      }
      __syncthreads();
      {
        const int c = tid;  // 0..511
        float a = 0.f;
        for (int q = 0; q < QL; q++) a += swgt[q] * qin[((size_t)q * BB + b) * EE + c];
        unsigned short hi, lo;
        split_bf(a, hi, lo);
        astu(&attp[((size_t)d * BB + b) * EE + c], ((unsigned)hi << 16) | lo);
      }
    }
    gbar(bar, ++gen);

    // ---------- phase B: gate partials (blocks 0-63) + gh (blocks 160-183) ----------
    if (blk < 64) {
      const int d = blk >> 5, r5 = blk & 31, nt = r5 >> 2, ks = r5 & 3;
      const int t = d ? (PL - 1 - s) : s;
      gemm_t<128, 1, false, false, true>(sAh, sAl, warea,
          nullptr, 0,
          pin + (size_t)t * BB * EE, attp + (size_t)d * BB * EE,
          nullptr, nullptr, d,
          nullptr, nullptr, 0,
          gp + (size_t)(d * 4 + ks) * BB * DD + nt * 128, DD, ks * 256, 4);
    } else if (blk >= 160 && blk < 184) {
      const int g = blk - 160, d = g / 12, nt = g % 12;
      gemm_t<64, 3, true, false, true>(sAh, sAl, warea,
          hbuf + (size_t)d * BB * HH, HH,
          nullptr, nullptr, nullptr, nullptr, 0,
          nullptr, nullptr, 0,
          ghp + (size_t)d * BB * G3 + nt * 64, G3, 0, 4);
    }
    gbar(bar, ++gen);

    // ---------- phase C1: gi partials (blocks 64-159), x gated inline ----------
    if (blk >= 64 && blk < 160) {
      const int g = blk - 64, d = g / 48, r = g % 48, nt = r >> 2, ks = r & 3;
      const int t = d ? (PL - 1 - s) : s;
      gemm_t<64, 2, true, false, true>(sAh, sAl, warea,
          nullptr, 0,
          pin + (size_t)t * BB * EE, attp + (size_t)d * BB * EE,
          gp, gateb + (size_t)d * DD, d,
          nullptr, nullptr, 0,
          gip + (size_t)(d * 4 + ks) * BB * G3 + nt * 64, G3, ks * 256, 4);
    }
    gbar(bar, ++gen);

    // ---------- phase C2: GRU elementwise + output + state_temp GEMV ----------
    {
      const int d = d_ab, b = b_ab;
      const int j = tid & 255, half = tid >> 8;
      const int t = d ? (PL - 1 - s) : s;
      const size_t rb = (size_t)d * BB + b;
      float gi0 = bih[(size_t)d * G3 + j];
      float gi1 = bih[(size_t)d * G3 + HH + j];
      float gi2 = bih[(size_t)d * G3 + 2 * HH + j];
#pragma unroll
      for (int k2 = 0; k2 < 4; k2++) {
        size_t ro = ((size_t)(d * 4 + k2) * BB + b) * G3;
        gi0 += ald(&gip[ro + j]);
        gi1 += ald(&gip[ro + HH + j]);
        gi2 += ald(&gip[ro + 2 * HH + j]);
      }
      size_t go = rb * G3;
      float gh0 = ald(&ghp[go + j]) + bhh[(size_t)d * G3 + j];
      float gh1 = ald(&ghp[go + HH + j]) + bhh[(size_t)d * G3 + HH + j];
      float gh2 = ald(&ghp[go + 2 * HH + j]) + bhh[(size_t)d * G3 + 2 * HH + j];
      float r = sigm(gi0 + gh0);
      float z = sigm(gi1 + gh1);
      float n = tanhf(gi2 + r * gh2);
      float hn = (1.f - z) * n + z * hreg;
      hreg = hn;
      if (half == 0) {
        out[((size_t)t * BB + b) * 512 + d * HH + j] = hn;
        ast(&hbuf[rb * HH + j], hn);
        hrow[j] = hn;
      }
      __syncthreads();
      // state_temp GEMV: stv[j] = sum_k h[k] * Ws[k][j], split over halves
      float part = 0.f;
      const float* wr = wst + ((size_t)d * HH + j) * HH + (half << 7);
      const float* hr = hrow + (half << 7);
#pragma unroll
      for (int k = 0; k < 128; k += 4) {
        float4 w4 = *(const float4*)&wr[k];
        float4 h4 = *(const float4*)&hr[k];
        part += w4.x * h4.x + w4.y * h4.y + w4.z * h4.z + w4.w * h4.w;
      }
      spart[tid] = part;
      __syncthreads();
      if (tid < 256) sstv[tid] = spart[tid] + spart[tid + 256];
      __syncthreads();
    }
    // C2 -> A: no barrier (A consumes only block-local sstv/hreg + static tensors)
  }
}

// ---------------- launch ----------------
extern "C" void kernel_launch(void* const* d_in, const int* in_sizes, int n_in,
                              void* d_out, int out_size, void* d_ws, size_t ws_size,
                              hipStream_t stream) {
  const float* qin = (const float*)d_in[0];
  const float* pin = (const float*)d_in[1];
  const unsigned char* qmask = (const unsigned char*)d_in[2];
  const float* Wq  = (const float*)d_in[3];
  const float* Wp  = (const float*)d_in[4];
  const float* Ws  = (const float*)d_in[5];
  const float* v   = (const float*)d_in[6];
  const float* gw  = (const float*)d_in[7];
  const float* gb  = (const float*)d_in[8];
  const float* wih = (const float*)d_in[9];
  const float* whh = (const float*)d_in[10];
  const float* bih = (const float*)d_in[11];
  const float* bhh = (const float*)d_in[12];
  float* out = (float*)d_out;

  float* fws = (float*)d_ws;
  unsigned short* hws = (unsigned short*)((char*)d_ws + F32_TOT * sizeof(float));
  unsigned* bar = (unsigned*)((char*)d_ws + F32_TOT * sizeof(float) + H_TOT * sizeof(unsigned short));
  size_t need = F32_TOT * sizeof(float) + H_TOT * sizeof(unsigned short) + 8192;
  if (ws_size < need) return;

  // zero GRU state + barrier slots (re-runs on every graph replay)
  hipMemsetAsync((char*)d_ws + OFF_H * sizeof(float), 0, SZ_H * sizeof(float), stream);
  hipMemsetAsync(bar, 0, 4096, stream);

  k_transpose_qp<<<128, 256, 0, stream>>>(Wq, Wp,
      hws + HOFF_WQTH, hws + HOFF_WQTL, hws + HOFF_WPTH, hws + HOFF_WPTL);
  k_split_w<<<1024, 256, 0, stream>>>(gw, wih, whh,
      hws + HOFF_GWH, hws + HOFF_GWL, hws + HOFF_WIHH, hws + HOFF_WIHL,
      hws + HOFF_WHHH, hws + HOFF_WHHL);
  k_wst<<<(int)((SZ_WST + 255) / 256), 256, 0, stream>>>(Ws, (float*)d_ws + OFF_WST);
  pe_main<<<NBLK, NTHR, 0, stream>>>(qin, pin, qmask, v, gb, bih, bhh, out, fws, hws, bar);
}